// Round 7
// baseline (693.624 us; speedup 1.0000x reference)
//
#include <hip/hip_runtime.h>

#define B_ 4
#define T_ 2048
#define C_ 1024

typedef unsigned short u16;
typedef unsigned int u32;
typedef short sh8 __attribute__((ext_vector_type(8)));   // 8 bf16 payload (4 VGPRs)
typedef float f32x4 __attribute__((ext_vector_type(4)));

__device__ __forceinline__ float bf2f(u16 u) {
    union { float f; u32 i; } c; c.i = ((u32)u) << 16; return c.f;
}
__device__ __forceinline__ u16 f2bf(float f) {
    union { float f; u32 i; } c; c.f = f;
    return (u16)((c.i + 0x7FFFu + ((c.i >> 16) & 1u)) >> 16);
}

// ---------------------------------------------------------------------------
// 128x128 TN MFMA core, bf16, BK=64, software-pipelined VGPR staging:
//   prologue: load tile 0 into regs
//   loop kt:  raw s_barrier (no vmcnt drain -> prefetch stays in flight)
//             ds_write regs -> LDS   (vmcnt wait lands here, ~1 kt after issue)
//             __syncthreads          (publish; vmcnt already 0 -> cheap)
//             issue prefetch loads for kt+1 (global -> VGPR, no wait)
//             compute 32 MFMA on LDS tile (hides prefetch latency)
// LDS granule swizzle: phys col = c ^ (row&7)  -> conflict-free b128 reads,
// applied on the ds_write scatter (per-lane scatter is legal for ds_write).
// RS: also accumulate row-sums of A via MFMA against a ones-fragment.
// ---------------------------------------------------------------------------
template<bool RS>
__device__ __forceinline__ void mm_core(
    const u16* __restrict__ A, const u16* __restrict__ B,
    int ldA, int ldB, int nk64,
    u16* lA, u16* lB, f32x4 (&acc)[4][4], f32x4* rsacc, int tid)
{
    const int w  = tid >> 6, l = tid & 63;
    const int fr = l & 15,  fq = l >> 4;
    const int wm = (w & 1) << 6, wn = (w >> 1) << 6;
    const int sr = tid >> 3;      // staging row base (0..31), rows sr+32t
    const int sc = tid & 7;       // staging logical granule col

    sh8 ones;
    if (RS) {
#pragma unroll
        for (int e = 0; e < 8; ++e) ones[e] = (short)0x3F80;  // bf16 1.0
    }

    uint4 ca[4], cb[4];
#pragma unroll
    for (int t = 0; t < 4; ++t) {                 // prologue: tile 0
        const int r = sr + 32 * t;
        ca[t] = *(const uint4*)(A + (size_t)r * ldA + sc * 8);
        cb[t] = *(const uint4*)(B + (size_t)r * ldB + sc * 8);
    }

    for (int kt = 0; kt < nk64; ++kt) {
        __builtin_amdgcn_s_barrier();             // readers of prev tile done
#pragma unroll
        for (int t = 0; t < 4; ++t) {
            const int r  = sr + 32 * t;
            const int pc = sc ^ (r & 7);
            *(uint4*)(lA + ((size_t)r * 8 + pc) * 8) = ca[t];
            *(uint4*)(lB + ((size_t)r * 8 + pc) * 8) = cb[t];
        }
        __syncthreads();                          // publish tile kt
        if (kt + 1 < nk64) {
            const int ko = (kt + 1) << 6;
#pragma unroll
            for (int t = 0; t < 4; ++t) {         // prefetch kt+1 (no wait)
                const int r = sr + 32 * t;
                ca[t] = *(const uint4*)(A + (size_t)r * ldA + ko + sc * 8);
                cb[t] = *(const uint4*)(B + (size_t)r * ldB + ko + sc * 8);
            }
        }
#pragma unroll
        for (int kk = 0; kk < 2; ++kk) {
            sh8 af[4], bf[4];
            const int g = kk * 4 + fq;
#pragma unroll
            for (int i = 0; i < 4; ++i) {
                const int m = wm + i * 16 + fr;
                af[i] = *(const sh8*)(lA + ((size_t)m * 8 + (g ^ (m & 7))) * 8);
                const int n = wn + i * 16 + fr;
                bf[i] = *(const sh8*)(lB + ((size_t)n * 8 + (g ^ (n & 7))) * 8);
            }
#pragma unroll
            for (int i = 0; i < 4; ++i) {
#pragma unroll
                for (int j = 0; j < 4; ++j)
                    acc[i][j] = __builtin_amdgcn_mfma_f32_16x16x32_bf16(af[i], bf[j], acc[i][j], 0, 0, 0);
                if (RS)
                    rsacc[i] = __builtin_amdgcn_mfma_f32_16x16x32_bf16(af[i], ones, rsacc[i], 0, 0, 0);
            }
        }
    }
}

// --------------------- conversions (fused) ----------------------------------
// blocks [0,8192): x fp32 -> bf16.  blocks [8192,8960): W -> W^T bf16 (x3).
__global__ __launch_bounds__(256) void cvt_all(
    const float* __restrict__ x,
    const float* __restrict__ Wq, const float* __restrict__ Wk, const float* __restrict__ Wv,
    u16* __restrict__ xb, u16* __restrict__ wt)
{
    __shared__ float tile[64][68];
    const int bid = blockIdx.x;
    if (bid < 8192) {
        size_t i = ((size_t)bid * 256 + threadIdx.x) * 4;
        float4 f = *(const float4*)(x + i);
        ushort4 o;
        o.x = f2bf(f.x); o.y = f2bf(f.y); o.z = f2bf(f.z); o.w = f2bf(f.w);
        *(ushort4*)(xb + i) = o;
        return;
    }
    const int r = bid - 8192;
    const int z = r >> 8;                  // 0..2
    const int rr = r & 255;
    const int n0 = (rr & 15) * 64, k0 = (rr >> 4) * 64;
    const float* W = z == 0 ? Wq : (z == 1 ? Wk : Wv);
    u16* out = wt + (size_t)z * C_ * C_;
    const int tx = threadIdx.x & 15, ty = threadIdx.x >> 4;
#pragma unroll
    for (int rr2 = 0; rr2 < 4; ++rr2) {
        int row = ty + rr2 * 16;
        *(float4*)&tile[row][tx * 4] = *(const float4*)(W + (size_t)(k0 + row) * C_ + n0 + tx * 4);
    }
    __syncthreads();
#pragma unroll
    for (int rr2 = 0; rr2 < 4; ++rr2) {
        int n = ty + rr2 * 16;
        ushort4 o;
        o.x = f2bf(tile[tx * 4 + 0][n]);
        o.y = f2bf(tile[tx * 4 + 1][n]);
        o.z = f2bf(tile[tx * 4 + 2][n]);
        o.w = f2bf(tile[tx * 4 + 3][n]);
        *(ushort4*)(out + (size_t)(n0 + n) * C_ + k0 + tx * 4) = o;
    }
}

// --------------------- q/k/v projections ------------------------------------
// grid (8, 64, 3). z==2 (v) writes TRANSPOSED vt[b][c][t] via LDS bounce.
__global__ __launch_bounds__(256, 4) void qkv_mfma(
    const u16* __restrict__ xb, const u16* __restrict__ wt,
    const float* __restrict__ bq, const float* __restrict__ bk, const float* __restrict__ bv,
    u16* __restrict__ qo, u16* __restrict__ ko, u16* __restrict__ vto)
{
    __shared__ __align__(16) u16 smem[17408];   // 34 KB: staging 32KB | bounce
    u16* lA = smem; u16* lB = smem + 8192;
    const int z = blockIdx.z;
    const u16* W = wt + (size_t)z * C_ * C_;
    const float* bias = z == 0 ? bq : (z == 1 ? bk : bv);
    const int n0 = blockIdx.x * 128, m0 = blockIdx.y * 128;
    const int tid = threadIdx.x;
    f32x4 acc[4][4];
#pragma unroll
    for (int i = 0; i < 4; ++i)
#pragma unroll
        for (int j = 0; j < 4; ++j) acc[i][j] = 0.0f;

    mm_core<false>(xb + (size_t)m0 * C_, W + (size_t)n0 * C_, C_, C_, C_ / 64, lA, lB, acc, nullptr, tid);
    __syncthreads();                            // staging dead, reuse as bounce

    const int w = tid >> 6, l = tid & 63, fr = l & 15, fq = l >> 4;
    const int wm = (w & 1) << 6, wn = (w >> 1) << 6;
    if (z < 2) {
#pragma unroll
        for (int i = 0; i < 4; ++i)
#pragma unroll
            for (int j = 0; j < 4; ++j) {
                const int ln = wn + j * 16 + fr;
                const float bb = bias[n0 + ln];
#pragma unroll
                for (int r = 0; r < 4; ++r) {
                    const int lm = wm + i * 16 + fq * 4 + r;
                    smem[lm * 136 + ln] = f2bf(acc[i][j][r] + bb);
                }
            }
        __syncthreads();
        u16* out = z == 0 ? qo : ko;
        const int rr = tid >> 4, cc = tid & 15;
#pragma unroll
        for (int p = 0; p < 8; ++p) {
            const int row = p * 16 + rr;
            uint4 val = *(const uint4*)&smem[row * 136 + cc * 8];
            *(uint4*)(out + (size_t)(m0 + row) * C_ + n0 + cc * 8) = val;
        }
    } else {
#pragma unroll
        for (int i = 0; i < 4; ++i)
#pragma unroll
            for (int j = 0; j < 4; ++j) {
                const int ln = wn + j * 16 + fr;
                const float bb = bias[n0 + ln];
#pragma unroll
                for (int r = 0; r < 4; ++r) {
                    const int lm = wm + i * 16 + fq * 4 + r;
                    smem[lm * 129 + ln] = f2bf(acc[i][j][r] + bb);
                }
            }
        __syncthreads();
        const int b = m0 >> 11;
        const int t0 = m0 & 2047;
        u16* vt = vto + (size_t)b * C_ * T_;
#pragma unroll
        for (int pass = 0; pass < 8; ++pass) {
            const int ln = (tid >> 4) + pass * 16;
            const int c  = tid & 15;
            u16 tmp[8];
#pragma unroll
            for (int e = 0; e < 8; ++e) tmp[e] = smem[(c * 8 + e) * 129 + ln];
            *(uint4*)(vt + (size_t)(n0 + ln) * T_ + t0 + c * 8) = *(uint4*)tmp;
        }
    }
}

// att per-batch offsets in u16 units: b0,b1 over xb region; b2,b3 over wt region.
__device__ __constant__ size_t att_off[4] = {
    0, (size_t)1 << 22, (size_t)1 << 25, ((size_t)1 << 25) + ((size_t)1 << 22)
};

// --------------------- scores: P = exp(q k^T / 32), causal ------------------
// grid (136, 1, 4): flattened lower-triangle tile index x batch.
__global__ __launch_bounds__(256, 4) void scores_mfma(
    const u16* __restrict__ qb, const u16* __restrict__ kb, u16* __restrict__ wsbase)
{
    int t = blockIdx.x;
    int by = (int)((sqrtf(8.f * t + 1.f) - 1.f) * 0.5f);
    while ((by + 1) * (by + 2) / 2 <= t) ++by;
    while (by * (by + 1) / 2 > t) --by;
    const int bx = t - by * (by + 1) / 2;
    const int b = blockIdx.z;
    const int s0 = bx * 128, m0 = by * 128;
    __shared__ __align__(16) u16 smem[17408];
    u16* lA = smem; u16* lB = smem + 8192;
    const u16* Q = qb + (size_t)b * T_ * C_ + (size_t)m0 * C_;
    const u16* K = kb + (size_t)b * T_ * C_ + (size_t)s0 * C_;
    const int tid = threadIdx.x;
    f32x4 acc[4][4];
#pragma unroll
    for (int i = 0; i < 4; ++i)
#pragma unroll
        for (int j = 0; j < 4; ++j) acc[i][j] = 0.0f;

    mm_core<false>(Q, K, C_, C_, C_ / 64, lA, lB, acc, nullptr, tid);
    __syncthreads();

    const int w = tid >> 6, l = tid & 63, fr = l & 15, fq = l >> 4;
    const int wm = (w & 1) << 6, wn = (w >> 1) << 6;
#pragma unroll
    for (int i = 0; i < 4; ++i)
#pragma unroll
        for (int r = 0; r < 4; ++r) {
            const int lm = wm + i * 16 + fq * 4 + r;
            const int m = m0 + lm;
#pragma unroll
            for (int j = 0; j < 4; ++j) {
                const int ls = wn + j * 16 + fr;
                const int s = s0 + ls;
                float e = (s <= m) ? __expf(acc[i][j][r] * 0.03125f) : 0.f;
                smem[lm * 136 + ls] = f2bf(e);
            }
        }
    __syncthreads();
    u16* att = wsbase + att_off[b] + (size_t)m0 * T_ + s0;
    const int rr = tid >> 4, cc = tid & 15;
#pragma unroll
    for (int p = 0; p < 8; ++p) {
        const int row = p * 16 + rr;
        uint4 val = *(const uint4*)&smem[row * 136 + cc * 8];
        *(uint4*)(att + (size_t)row * T_ + cc * 8) = val;
    }
}

// --------------------- O = (P v) / rowsum -----------------------------------
// grid (8, 16, 4), heavy m-tiles first. Rowsum via MFMA-with-ones in mm_core.
__global__ __launch_bounds__(256, 3) void pv_mfma(
    const u16* __restrict__ wsbase, const u16* __restrict__ vt,
    float* __restrict__ outp)
{
    const int b = blockIdx.z;
    const int n0 = blockIdx.x * 128;
    const int by = 15 - blockIdx.y;            // heavy (long-K) tiles first
    const int m0 = by * 128;
    __shared__ __align__(16) u16 smem[17408];
    u16* lA = smem; u16* lB = smem + 8192;
    const u16* A  = wsbase + att_off[b] + (size_t)m0 * T_;
    const u16* Bp = vt + (size_t)b * C_ * T_ + (size_t)n0 * T_;
    const int tid = threadIdx.x;
    f32x4 acc[4][4], rs[4];
#pragma unroll
    for (int i = 0; i < 4; ++i) {
        rs[i] = 0.0f;
#pragma unroll
        for (int j = 0; j < 4; ++j) acc[i][j] = 0.0f;
    }

    mm_core<true>(A, Bp, T_, T_, (m0 + 128) >> 6, lA, lB, acc, rs, tid);
    __syncthreads();

    const int w = tid >> 6, l = tid & 63, fr = l & 15, fq = l >> 4;
    const int wm = (w & 1) << 6, wn = (w >> 1) << 6;
    float* fb = (float*)smem;                  // 64 x 132 f32 bounce
#pragma unroll
    for (int p = 0; p < 2; ++p) {
        if ((w & 1) == p) {
#pragma unroll
            for (int i = 0; i < 4; ++i)
#pragma unroll
                for (int r = 0; r < 4; ++r) {
                    const int rr2 = i * 16 + fq * 4 + r;
                    const float inv = 1.0f / rs[i][r];
#pragma unroll
                    for (int j = 0; j < 4; ++j)
                        fb[rr2 * 132 + wn + j * 16 + fr] = acc[i][j][r] * inv;
                }
        }
        __syncthreads();
        const int rr = tid >> 5, cc = (tid & 31) * 4;
#pragma unroll
        for (int k2 = 0; k2 < 8; ++k2) {
            const int row = k2 * 8 + rr;
            float4 val = *(const float4*)&fb[row * 132 + cc];
            *(float4*)(outp + ((size_t)b * T_ + m0 + p * 64 + row) * C_ + n0 + cc) = val;
        }
        __syncthreads();
    }
}

extern "C" void kernel_launch(void* const* d_in, const int* in_sizes, int n_in,
                              void* d_out, int out_size, void* d_ws, size_t ws_size,
                              hipStream_t stream) {
    const float* x  = (const float*)d_in[0];
    const float* Wq = (const float*)d_in[1];
    const float* bq = (const float*)d_in[2];
    const float* Wk = (const float*)d_in[3];
    const float* bk = (const float*)d_in[4];
    const float* Wv = (const float*)d_in[5];
    const float* bv = (const float*)d_in[6];
    float* out = (float*)d_out;

    // workspace (80 MB):
    //   [ 0,16M) xb   -> dead after qkv; att batches 0,1 overlay
    //   [16,32M) q
    //   [32,48M) k
    //   [48,64M) vt   (v transposed [b][c][t])
    //   [64,70M) wt   -> dead after qkv; att batches 2,3 overlay [64,80M)
    char* ws = (char*)d_ws;
    u16* xb   = (u16*)ws;
    u16* q    = (u16*)(ws + (16ull << 20));
    u16* k    = (u16*)(ws + (32ull << 20));
    u16* vt   = (u16*)(ws + (48ull << 20));
    u16* wt   = (u16*)(ws + (64ull << 20));
    u16* attb = (u16*)ws;   // att_off[] indexes from workspace base

    cvt_all <<<8960, 256, 0, stream>>>(x, Wq, Wk, Wv, xb, wt);
    qkv_mfma<<<dim3(8, 64, 3), 256, 0, stream>>>(xb, wt, bq, bk, bv, q, k, vt);
    scores_mfma<<<dim3(136, 1, 4), 256, 0, stream>>>(q, k, attb);
    pv_mfma    <<<dim3(8, 16, 4), 256, 0, stream>>>(attb, vt, out);
}

// Round 8
// 246.571 us; speedup vs baseline: 2.8131x; 2.8131x over previous
//
#include <hip/hip_runtime.h>

#define B_ 4
#define T_ 2048
#define C_ 1024

typedef unsigned short u16;
typedef unsigned int u32;
typedef short sh8 __attribute__((ext_vector_type(8)));   // 8 bf16 payload (4 VGPRs)
typedef float f32x4 __attribute__((ext_vector_type(4)));

__device__ __forceinline__ float bf2f(u16 u) {
    union { float f; u32 i; } c; c.i = ((u32)u) << 16; return c.f;
}
__device__ __forceinline__ u16 f2bf(float f) {
    union { float f; u32 i; } c; c.f = f;
    return (u16)((c.i + 0x7FFFu + ((c.i >> 16) & 1u)) >> 16);
}

// async 16B/lane global->LDS. Dest = wave-uniform base + lane*16.
__device__ __forceinline__ void gload_lds16(const void* g, void* l) {
    __builtin_amdgcn_global_load_lds(
        (const __attribute__((address_space(1))) u32*)g,
        (__attribute__((address_space(3))) u32*)l, 16, 0, 0);
}

__device__ __forceinline__ void wait_vm8()   { asm volatile("s_waitcnt vmcnt(8)" ::: "memory"); }
__device__ __forceinline__ void wait_vm0()   { asm volatile("s_waitcnt vmcnt(0)" ::: "memory"); }
__device__ __forceinline__ void barrier_raw(){ asm volatile("s_barrier" ::: "memory"); }

// ---------------------------------------------------------------------------
// 128x128 TN MFMA core, bf16, BK=64, DOUBLE-BUFFERED global_load_lds:
//   prologue: DMA tiles 0,1 into buf0,buf1 (16 loads/wave in flight)
//   iter kt:  s_waitcnt vmcnt(8)  -- own tile-kt loads landed (kt+1 in flight)
//             s_barrier (raw)     -- join: whole block's kt loads landed
//             compute 32 MFMA on buf[kt&1]   (kt+1 DMA flies underneath)
//             s_barrier (raw)     -- all waves done reading buf[kt&1]
//             DMA tile kt+2 -> buf[kt&1]
// LDS: A0 @0, B0 @8192, A1 @16384, B1 @24576 (u16 units) = 64 KB.
// Granule swizzle: phys col = c ^ (row&7), applied in the lane->global mapping
// (free); fragment ds_read_b128 sees only the free 2-way aliasing.
// RS: also accumulate row-sums of A via MFMA against a ones-fragment.
// ---------------------------------------------------------------------------
template<bool RS>
__device__ __forceinline__ void mm_core(
    const u16* __restrict__ A, const u16* __restrict__ B,
    int ldA, int ldB, int nk64,
    u16* lds, f32x4 (&acc)[4][4], f32x4* rsacc, int tid)
{
    const int w  = tid >> 6, l = tid & 63;
    const int fr = l & 15,  fq = l >> 4;
    const int wm = (w & 1) << 6, wn = (w >> 1) << 6;
    const int rl = l >> 3;            // row within 8-row group
    const int pc = l & 7;             // phys granule col this lane fills
    const int cg = pc ^ rl;           // logical granule to fetch

    sh8 ones;
    if (RS) {
#pragma unroll
        for (int e = 0; e < 8; ++e) ones[e] = (short)0x3F80;  // bf16 1.0
    }

    auto issue = [&](int kt) {
        const int ko = kt << 6;
        u16* dA = lds + ((kt & 1) << 14);
        u16* dB = dA + 8192;
#pragma unroll
        for (int t = 0; t < 4; ++t) {
            const int r0 = w * 32 + t * 8;
            const int r  = r0 + rl;
            gload_lds16(A + (size_t)r * ldA + ko + cg * 8, dA + ((size_t)r0 * 8 + l) * 8);
            gload_lds16(B + (size_t)r * ldB + ko + cg * 8, dB + ((size_t)r0 * 8 + l) * 8);
        }
    };

    issue(0);
    issue(1);

    for (int kt = 0; kt < nk64; ++kt) {
        if (kt + 1 < nk64) wait_vm8(); else wait_vm0();
        barrier_raw();                       // block-wide: tile kt resident
        u16* bufA = lds + ((kt & 1) << 14);
        u16* bufB = bufA + 8192;
#pragma unroll
        for (int kk = 0; kk < 2; ++kk) {
            sh8 af[4], bf[4];
            const int g = kk * 4 + fq;
#pragma unroll
            for (int i = 0; i < 4; ++i) {
                const int m = wm + i * 16 + fr;
                af[i] = *(const sh8*)(bufA + ((size_t)m * 8 + (g ^ (m & 7))) * 8);
                const int n = wn + i * 16 + fr;
                bf[i] = *(const sh8*)(bufB + ((size_t)n * 8 + (g ^ (n & 7))) * 8);
            }
#pragma unroll
            for (int i = 0; i < 4; ++i) {
#pragma unroll
                for (int j = 0; j < 4; ++j)
                    acc[i][j] = __builtin_amdgcn_mfma_f32_16x16x32_bf16(af[i], bf[j], acc[i][j], 0, 0, 0);
                if (RS)
                    rsacc[i] = __builtin_amdgcn_mfma_f32_16x16x32_bf16(af[i], ones, rsacc[i], 0, 0, 0);
            }
        }
        barrier_raw();                       // all waves done reading buf[kt&1]
        if (kt + 2 < nk64) issue(kt + 2);
    }
}

// --------------------- conversions (fused) ----------------------------------
// blocks [0,8192): x fp32 -> bf16.  blocks [8192,8960): W -> W^T bf16 (x3).
__global__ __launch_bounds__(256) void cvt_all(
    const float* __restrict__ x,
    const float* __restrict__ Wq, const float* __restrict__ Wk, const float* __restrict__ Wv,
    u16* __restrict__ xb, u16* __restrict__ wt)
{
    __shared__ float tile[64][68];
    const int bid = blockIdx.x;
    if (bid < 8192) {
        size_t i = ((size_t)bid * 256 + threadIdx.x) * 4;
        float4 f = *(const float4*)(x + i);
        ushort4 o;
        o.x = f2bf(f.x); o.y = f2bf(f.y); o.z = f2bf(f.z); o.w = f2bf(f.w);
        *(ushort4*)(xb + i) = o;
        return;
    }
    const int r = bid - 8192;
    const int z = r >> 8;                  // 0..2
    const int rr = r & 255;
    const int n0 = (rr & 15) * 64, k0 = (rr >> 4) * 64;
    const float* W = z == 0 ? Wq : (z == 1 ? Wk : Wv);
    u16* out = wt + (size_t)z * C_ * C_;
    const int tx = threadIdx.x & 15, ty = threadIdx.x >> 4;
#pragma unroll
    for (int rr2 = 0; rr2 < 4; ++rr2) {
        int row = ty + rr2 * 16;
        *(float4*)&tile[row][tx * 4] = *(const float4*)(W + (size_t)(k0 + row) * C_ + n0 + tx * 4);
    }
    __syncthreads();
#pragma unroll
    for (int rr2 = 0; rr2 < 4; ++rr2) {
        int n = ty + rr2 * 16;
        ushort4 o;
        o.x = f2bf(tile[tx * 4 + 0][n]);
        o.y = f2bf(tile[tx * 4 + 1][n]);
        o.z = f2bf(tile[tx * 4 + 2][n]);
        o.w = f2bf(tile[tx * 4 + 3][n]);
        *(ushort4*)(out + (size_t)(n0 + n) * C_ + k0 + tx * 4) = o;
    }
}

// --------------------- q/k/v projections ------------------------------------
// grid (8, 64, 3). z==2 (v) writes TRANSPOSED vt[b][c][t] via LDS bounce.
__global__ __launch_bounds__(256, 2) void qkv_mfma(
    const u16* __restrict__ xb, const u16* __restrict__ wt,
    const float* __restrict__ bq, const float* __restrict__ bk, const float* __restrict__ bv,
    u16* __restrict__ qo, u16* __restrict__ ko, u16* __restrict__ vto)
{
    __shared__ __align__(16) u16 smem[32768];   // 64 KB: dbuf staging | bounce
    const int z = blockIdx.z;
    const u16* W = wt + (size_t)z * C_ * C_;
    const float* bias = z == 0 ? bq : (z == 1 ? bk : bv);
    const int n0 = blockIdx.x * 128, m0 = blockIdx.y * 128;
    const int tid = threadIdx.x;
    f32x4 acc[4][4];
#pragma unroll
    for (int i = 0; i < 4; ++i)
#pragma unroll
        for (int j = 0; j < 4; ++j) acc[i][j] = 0.0f;

    mm_core<false>(xb + (size_t)m0 * C_, W + (size_t)n0 * C_, C_, C_, C_ / 64, smem, acc, nullptr, tid);

    const int w = tid >> 6, l = tid & 63, fr = l & 15, fq = l >> 4;
    const int wm = (w & 1) << 6, wn = (w >> 1) << 6;
    if (z < 2) {
#pragma unroll
        for (int i = 0; i < 4; ++i)
#pragma unroll
            for (int j = 0; j < 4; ++j) {
                const int ln = wn + j * 16 + fr;
                const float bb = bias[n0 + ln];
#pragma unroll
                for (int r = 0; r < 4; ++r) {
                    const int lm = wm + i * 16 + fq * 4 + r;
                    smem[lm * 136 + ln] = f2bf(acc[i][j][r] + bb);
                }
            }
        __syncthreads();
        u16* out = z == 0 ? qo : ko;
        const int rr = tid >> 4, cc = tid & 15;
#pragma unroll
        for (int p = 0; p < 8; ++p) {
            const int row = p * 16 + rr;
            uint4 val = *(const uint4*)&smem[row * 136 + cc * 8];
            *(uint4*)(out + (size_t)(m0 + row) * C_ + n0 + cc * 8) = val;
        }
    } else {
#pragma unroll
        for (int i = 0; i < 4; ++i)
#pragma unroll
            for (int j = 0; j < 4; ++j) {
                const int ln = wn + j * 16 + fr;
                const float bb = bias[n0 + ln];
#pragma unroll
                for (int r = 0; r < 4; ++r) {
                    const int lm = wm + i * 16 + fq * 4 + r;
                    smem[lm * 129 + ln] = f2bf(acc[i][j][r] + bb);
                }
            }
        __syncthreads();
        const int b = m0 >> 11;
        const int t0 = m0 & 2047;
        u16* vt = vto + (size_t)b * C_ * T_;
#pragma unroll
        for (int pass = 0; pass < 8; ++pass) {
            const int ln = (tid >> 4) + pass * 16;
            const int c  = tid & 15;
            u16 tmp[8];
#pragma unroll
            for (int e = 0; e < 8; ++e) tmp[e] = smem[(c * 8 + e) * 129 + ln];
            *(uint4*)(vt + (size_t)(n0 + ln) * T_ + t0 + c * 8) = *(uint4*)tmp;
        }
    }
}

// att per-batch offsets in u16 units: b0,b1 over xb region; b2,b3 over wt region.
__device__ __constant__ size_t att_off[4] = {
    0, (size_t)1 << 22, (size_t)1 << 25, ((size_t)1 << 25) + ((size_t)1 << 22)
};

// --------------------- scores: P = exp(q k^T / 32), causal ------------------
// grid (136, 1, 4): flattened lower-triangle tile index x batch.
__global__ __launch_bounds__(256, 2) void scores_mfma(
    const u16* __restrict__ qb, const u16* __restrict__ kb, u16* __restrict__ wsbase)
{
    int t = blockIdx.x;
    int by = (int)((sqrtf(8.f * t + 1.f) - 1.f) * 0.5f);
    while ((by + 1) * (by + 2) / 2 <= t) ++by;
    while (by * (by + 1) / 2 > t) --by;
    const int bx = t - by * (by + 1) / 2;
    const int b = blockIdx.z;
    const int s0 = bx * 128, m0 = by * 128;
    __shared__ __align__(16) u16 smem[32768];
    const u16* Q = qb + (size_t)b * T_ * C_ + (size_t)m0 * C_;
    const u16* K = kb + (size_t)b * T_ * C_ + (size_t)s0 * C_;
    const int tid = threadIdx.x;
    f32x4 acc[4][4];
#pragma unroll
    for (int i = 0; i < 4; ++i)
#pragma unroll
        for (int j = 0; j < 4; ++j) acc[i][j] = 0.0f;

    mm_core<false>(Q, K, C_, C_, C_ / 64, smem, acc, nullptr, tid);

    const int w = tid >> 6, l = tid & 63, fr = l & 15, fq = l >> 4;
    const int wm = (w & 1) << 6, wn = (w >> 1) << 6;
#pragma unroll
    for (int i = 0; i < 4; ++i)
#pragma unroll
        for (int r = 0; r < 4; ++r) {
            const int lm = wm + i * 16 + fq * 4 + r;
            const int m = m0 + lm;
#pragma unroll
            for (int j = 0; j < 4; ++j) {
                const int ls = wn + j * 16 + fr;
                const int s = s0 + ls;
                float e = (s <= m) ? __expf(acc[i][j][r] * 0.03125f) : 0.f;
                smem[lm * 136 + ls] = f2bf(e);
            }
        }
    __syncthreads();
    u16* att = wsbase + att_off[b] + (size_t)m0 * T_ + s0;
    const int rr = tid >> 4, cc = tid & 15;
#pragma unroll
    for (int p = 0; p < 8; ++p) {
        const int row = p * 16 + rr;
        uint4 val = *(const uint4*)&smem[row * 136 + cc * 8];
        *(uint4*)(att + (size_t)row * T_ + cc * 8) = val;
    }
}

// --------------------- O = (P v) / rowsum -----------------------------------
// grid (8, 16, 4), heavy m-tiles first. Rowsum via MFMA-with-ones in mm_core.
__global__ __launch_bounds__(256, 2) void pv_mfma(
    const u16* __restrict__ wsbase, const u16* __restrict__ vt,
    float* __restrict__ outp)
{
    const int b = blockIdx.z;
    const int n0 = blockIdx.x * 128;
    const int by = 15 - blockIdx.y;            // heavy (long-K) tiles first
    const int m0 = by * 128;
    __shared__ __align__(16) u16 smem[32768];
    const u16* A  = wsbase + att_off[b] + (size_t)m0 * T_;
    const u16* Bp = vt + (size_t)b * C_ * T_ + (size_t)n0 * T_;
    const int tid = threadIdx.x;
    f32x4 acc[4][4], rs[4];
#pragma unroll
    for (int i = 0; i < 4; ++i) {
        rs[i] = 0.0f;
#pragma unroll
        for (int j = 0; j < 4; ++j) acc[i][j] = 0.0f;
    }

    mm_core<true>(A, Bp, T_, T_, (m0 + 128) >> 6, smem, acc, rs, tid);

    const int w = tid >> 6, l = tid & 63, fr = l & 15, fq = l >> 4;
    const int wm = (w & 1) << 6, wn = (w >> 1) << 6;
    float* fb = (float*)smem;                  // 64 x 132 f32 bounce
#pragma unroll
    for (int p = 0; p < 2; ++p) {
        if ((w & 1) == p) {
#pragma unroll
            for (int i = 0; i < 4; ++i)
#pragma unroll
                for (int r = 0; r < 4; ++r) {
                    const int rr2 = i * 16 + fq * 4 + r;
                    const float inv = 1.0f / rs[i][r];
#pragma unroll
                    for (int j = 0; j < 4; ++j)
                        fb[rr2 * 132 + wn + j * 16 + fr] = acc[i][j][r] * inv;
                }
        }
        __syncthreads();
        const int rr = tid >> 5, cc = (tid & 31) * 4;
#pragma unroll
        for (int k2 = 0; k2 < 8; ++k2) {
            const int row = k2 * 8 + rr;
            float4 val = *(const float4*)&fb[row * 132 + cc];
            *(float4*)(outp + ((size_t)b * T_ + m0 + p * 64 + row) * C_ + n0 + cc) = val;
        }
        __syncthreads();
    }
}

extern "C" void kernel_launch(void* const* d_in, const int* in_sizes, int n_in,
                              void* d_out, int out_size, void* d_ws, size_t ws_size,
                              hipStream_t stream) {
    const float* x  = (const float*)d_in[0];
    const float* Wq = (const float*)d_in[1];
    const float* bq = (const float*)d_in[2];
    const float* Wk = (const float*)d_in[3];
    const float* bk = (const float*)d_in[4];
    const float* Wv = (const float*)d_in[5];
    const float* bv = (const float*)d_in[6];
    float* out = (float*)d_out;

    // workspace (80 MB):
    //   [ 0,16M) xb   -> dead after qkv; att batches 0,1 overlay
    //   [16,32M) q
    //   [32,48M) k
    //   [48,64M) vt   (v transposed [b][c][t])
    //   [64,70M) wt   -> dead after qkv; att batches 2,3 overlay [64,80M)
    char* ws = (char*)d_ws;
    u16* xb   = (u16*)ws;
    u16* q    = (u16*)(ws + (16ull << 20));
    u16* k    = (u16*)(ws + (32ull << 20));
    u16* vt   = (u16*)(ws + (48ull << 20));
    u16* wt   = (u16*)(ws + (64ull << 20));
    u16* attb = (u16*)ws;   // att_off[] indexes from workspace base

    cvt_all <<<8960, 256, 0, stream>>>(x, Wq, Wk, Wv, xb, wt);
    qkv_mfma<<<dim3(8, 64, 3), 256, 0, stream>>>(xb, wt, bq, bk, bv, q, k, vt);
    scores_mfma<<<dim3(136, 1, 4), 256, 0, stream>>>(q, k, attb);
    pv_mfma    <<<dim3(8, 16, 4), 256, 0, stream>>>(attb, vt, out);
}